// Round 1
// baseline (452.378 us; speedup 1.0000x reference)
//
#include <hip/hip_runtime.h>
#include <hip/hip_bf16.h>

#define SCALE 0.35355339059327373f

struct ProjW {
  const float* w[6];
  const float* b[6];
};

// ---- pack geo_mask [512][512] int -> bitmask [512][8] u64 ----
__global__ void k_pack_mask(const int* __restrict__ mask, unsigned long long* __restrict__ mb) {
  int w = blockIdx.x * blockDim.x + threadIdx.x;   // 0..4095
  if (w >= 4096) return;
  int n = w >> 3, wi = w & 7;
  const int* mp = mask + n * 512 + wi * 64;
  unsigned long long bits = 0ull;
  #pragma unroll
  for (int j = 0; j < 64; ++j) bits |= (mp[j] != 0) ? (1ull << j) : 0ull;
  mb[w] = bits;
}

// ---- x1[bt][n][32] = W1[32x64] * x[b,:,t,n] + b1 ----
__global__ void k_x1(const float* __restrict__ x, const float* __restrict__ w1,
                     const float* __restrict__ b1, float* __restrict__ x1) {
  int bt = blockIdx.x;        // 0..95
  int n  = threadIdx.x;       // 0..511
  int b = bt / 12, t = bt % 12;
  float acc[32];
  #pragma unroll
  for (int c = 0; c < 32; ++c) acc[c] = b1[c];
  const float* xp = x + ((size_t)(b * 64) * 12 + t) * 512 + n;
  for (int d = 0; d < 64; ++d) {
    float xd = xp[(size_t)d * 6144];
    #pragma unroll
    for (int c = 0; c < 32; ++c) acc[c] = fmaf(w1[c * 64 + d], xd, acc[c]);
  }
  float* o = x1 + ((size_t)bt * 512 + n) * 32;
  #pragma unroll
  for (int c = 0; c < 32; c += 4)
    *(float4*)(o + c) = make_float4(acc[c], acc[c+1], acc[c+2], acc[c+3]);
}

// ---- qkv[blk][bt][h][m][n][8] = W_p[32x32] * x1[bt][n][:] + b_p ----
__global__ void k_qkv(const float* __restrict__ x1, ProjW pw, float* __restrict__ qkv) {
  int chunk = blockIdx.x;     // 0..1
  int p     = blockIdx.y;     // 0..5 (blk*3 + m)
  int bt    = blockIdx.z;     // 0..95
  int n = chunk * 256 + threadIdx.x;
  const float* W = pw.w[p];
  const float* B = pw.b[p];
  float xv[32];
  const float* xp = x1 + ((size_t)bt * 512 + n) * 32;
  #pragma unroll
  for (int c = 0; c < 32; c += 4) {
    float4 v = *(const float4*)(xp + c);
    xv[c] = v.x; xv[c+1] = v.y; xv[c+2] = v.z; xv[c+3] = v.w;
  }
  float acc[32];
  #pragma unroll
  for (int c = 0; c < 32; ++c) acc[c] = B[c];
  #pragma unroll
  for (int d = 0; d < 32; ++d) {
    float xd = xv[d];
    #pragma unroll
    for (int c = 0; c < 32; ++c) acc[c] = fmaf(W[c * 32 + d], xd, acc[c]);
  }
  int blk = p / 3, m = p % 3;
  #pragma unroll
  for (int h = 0; h < 4; ++h) {
    size_t base = (((((size_t)blk * 96 + bt) * 4 + h) * 3 + m) * 512 + n) * 8;
    *(float4*)(qkv + base)     = make_float4(acc[h*8+0], acc[h*8+1], acc[h*8+2], acc[h*8+3]);
    *(float4*)(qkv + base + 4) = make_float4(acc[h*8+4], acc[h*8+5], acc[h*8+6], acc[h*8+7]);
  }
}

// ---- attention for one (blk): grid (h=4, bt=96), 512 threads = 1 query row each ----
template<bool MASKED>
__global__ void __launch_bounds__(512) k_attn(const float* __restrict__ qkvp,
                                              const unsigned long long* __restrict__ mb,
                                              float* __restrict__ obuf) {
  __shared__ float Ks[512][8];
  __shared__ float Vs[512][8];
  __shared__ unsigned long long mrow[MASKED ? 4096 : 8];
  int h  = blockIdx.x;   // 0..3
  int bt = blockIdx.y;   // 0..95
  int n  = threadIdx.x;  // 0..511
  size_t base = (((size_t)bt * 4 + h) * 3) * 4096;   // qkvp pre-offset by blk
  const float* Q = qkvp + base;
  const float* K = Q + 4096;
  const float* V = Q + 8192;
  *(float4*)&Ks[n][0] = *(const float4*)(K + (size_t)n * 8);
  *(float4*)&Ks[n][4] = *(const float4*)(K + (size_t)n * 8 + 4);
  *(float4*)&Vs[n][0] = *(const float4*)(V + (size_t)n * 8);
  *(float4*)&Vs[n][4] = *(const float4*)(V + (size_t)n * 8 + 4);
  if (MASKED) {
    for (int i = threadIdx.x; i < 4096; i += 512) mrow[i] = mb[i];
  }
  __syncthreads();
  float4 qa = *(const float4*)(Q + (size_t)n * 8);
  float4 qb = *(const float4*)(Q + (size_t)n * 8 + 4);

  float mx = -3.0e38f;
  unsigned long long mw = 0ull;
  #pragma unroll 4
  for (int j = 0; j < 512; ++j) {
    if (MASKED && (j & 63) == 0) mw = mrow[(n << 3) + (j >> 6)];
    float4 k0 = *(float4*)&Ks[j][0];
    float4 k1 = *(float4*)&Ks[j][4];
    float s = qa.x*k0.x + qa.y*k0.y + qa.z*k0.z + qa.w*k0.w
            + qb.x*k1.x + qb.y*k1.y + qb.z*k1.z + qb.w*k1.w;
    s *= SCALE;
    if (MASKED && ((mw >> (j & 63)) & 1ull)) s = -3.0e38f;
    mx = fmaxf(mx, s);
  }

  float l = 0.f;
  float a0=0,a1=0,a2=0,a3=0,a4=0,a5=0,a6=0,a7=0;
  #pragma unroll 4
  for (int j = 0; j < 512; ++j) {
    if (MASKED && (j & 63) == 0) mw = mrow[(n << 3) + (j >> 6)];
    float4 k0 = *(float4*)&Ks[j][0];
    float4 k1 = *(float4*)&Ks[j][4];
    float s = qa.x*k0.x + qa.y*k0.y + qa.z*k0.z + qa.w*k0.w
            + qb.x*k1.x + qb.y*k1.y + qb.z*k1.z + qb.w*k1.w;
    s *= SCALE;
    if (MASKED && ((mw >> (j & 63)) & 1ull)) s = -3.0e38f;
    float pe = __expf(s - mx);
    l += pe;
    float4 v0 = *(float4*)&Vs[j][0];
    float4 v1 = *(float4*)&Vs[j][4];
    a0 = fmaf(pe, v0.x, a0); a1 = fmaf(pe, v0.y, a1);
    a2 = fmaf(pe, v0.z, a2); a3 = fmaf(pe, v0.w, a3);
    a4 = fmaf(pe, v1.x, a4); a5 = fmaf(pe, v1.y, a5);
    a6 = fmaf(pe, v1.z, a6); a7 = fmaf(pe, v1.w, a7);
  }
  float inv = 1.0f / l;
  // o2[b,h,t,n,d] -> flat f = ((h*12+t)*512+n)*8+d; store as [b][n'][t'][c']:
  // index = (b*6144 + g)*32 + 8*(n&3) + d, g = (h*12+t)*128 + (n>>2)
  int b = bt / 12, t = bt % 12;
  int g = (h * 12 + t) * 128 + (n >> 2);
  size_t oidx = ((size_t)b * 6144 + g) * 32 + ((n & 3) << 3);
  *(float4*)(obuf + oidx)     = make_float4(a0*inv, a1*inv, a2*inv, a3*inv);
  *(float4*)(obuf + oidx + 4) = make_float4(a4*inv, a5*inv, a6*inv, a7*inv);
}

// ---- epilogue: out[b][c][t][n] = relu(obuf[sel][b][n][t][c&31] + x[b][c][t][n]) ----
__global__ void k_out(const float* __restrict__ x, const float* __restrict__ obuf,
                      float* __restrict__ out) {
  int idx = blockIdx.x * 256 + threadIdx.x;   // 0..3145727
  int n = idx & 511;
  int t = (idx >> 9) % 12;
  int c = (idx / 6144) & 63;
  int b = idx / 393216;
  int sel = c >> 5;               // 0 -> plain (x_v), 1 -> geo (x_geo_v)
  size_t oi = (size_t)sel * 1572864 + ((size_t)b * 6144 + (size_t)n * 12 + t) * 32 + (c & 31);
  float v = obuf[oi] + x[idx];
  out[idx] = fmaxf(v, 0.f);
}

extern "C" void kernel_launch(void* const* d_in, const int* in_sizes, int n_in,
                              void* d_out, int out_size, void* d_ws, size_t ws_size,
                              hipStream_t stream) {
  const float* x        = (const float*)d_in[0];
  const int*   geo_mask = (const int*)d_in[1];
  const float* w_proj1  = (const float*)d_in[2];
  const float* b_proj1  = (const float*)d_in[3];
  const float* wgq = (const float*)d_in[4];
  const float* bgq = (const float*)d_in[5];
  const float* wgk = (const float*)d_in[6];
  const float* bgk = (const float*)d_in[7];
  const float* wgv = (const float*)d_in[8];
  const float* bgv = (const float*)d_in[9];
  const float* wq  = (const float*)d_in[10];
  const float* bq  = (const float*)d_in[11];
  const float* wk  = (const float*)d_in[12];
  const float* bk  = (const float*)d_in[13];
  const float* wv  = (const float*)d_in[14];
  const float* bv  = (const float*)d_in[15];
  float* out = (float*)d_out;

  float* ws = (float*)d_ws;
  float* x1   = ws;                       // 96*512*32            = 1,572,864
  float* qkv  = ws + 1572864;             // 2*96*4*3*512*8       = 9,437,184
  float* obuf = ws + 11010048;            // 2 * 8*512*12*32      = 3,145,728
  unsigned long long* maskbits = (unsigned long long*)(ws + 14155776);  // 4096 u64

  k_pack_mask<<<16, 256, 0, stream>>>(geo_mask, maskbits);
  k_x1<<<96, 512, 0, stream>>>(x, w_proj1, b_proj1, x1);

  ProjW pw;
  // blk 0 = plain (x_v), blk 1 = geo (x_geo_v); m: 0=q,1=k,2=v
  pw.w[0] = wq;  pw.b[0] = bq;
  pw.w[1] = wk;  pw.b[1] = bk;
  pw.w[2] = wv;  pw.b[2] = bv;
  pw.w[3] = wgq; pw.b[3] = bgq;
  pw.w[4] = wgk; pw.b[4] = bgk;
  pw.w[5] = wgv; pw.b[5] = bgv;
  k_qkv<<<dim3(2, 6, 96), 256, 0, stream>>>(x1, pw, qkv);

  // plain block (no mask)
  k_attn<false><<<dim3(4, 96), 512, 0, stream>>>(qkv, nullptr, obuf);
  // geo block (masked); qkv blk-stride = 96*4*3*4096 = 4,718,592 floats
  k_attn<true><<<dim3(4, 96), 512, 0, stream>>>(qkv + 4718592, maskbits, obuf + 1572864);

  k_out<<<12288, 256, 0, stream>>>(x, obuf, out);
}

// Round 2
// 295.980 us; speedup vs baseline: 1.5284x; 1.5284x over previous
//
#include <hip/hip_runtime.h>
#include <hip/hip_bf16.h>

#define SCALE 0.35355339059327373f

struct ProjW {
  const float* w[6];
  const float* b[6];
};

// ---- pack geo_mask [512][512] int -> bitmask [512][16] u32 ----
__global__ void k_pack_mask(const int* __restrict__ mask, unsigned* __restrict__ mbw) {
  int w = blockIdx.x * 256 + threadIdx.x;   // 0..8191
  int n = w >> 4, wi = w & 15;
  const int* mp = mask + n * 512 + wi * 32;
  unsigned bits = 0u;
  #pragma unroll
  for (int j = 0; j < 32; ++j) bits |= (mp[j] != 0) ? (1u << j) : 0u;
  mbw[w] = bits;
}

// ---- fused weights: wf[p][32][64] = W_p * W1 ; bfv[p][32] = W_p*b1 + b_p ----
// p%3==0 (q proj): fold SCALE into weights+bias.
__global__ void k_wfuse(ProjW pw, const float* __restrict__ w1, const float* __restrict__ b1,
                        float* __restrict__ wf, float* __restrict__ bfv) {
  int p = blockIdx.x;       // 0..5
  int d = threadIdx.x;      // 0..63
  const float* W = pw.w[p];
  float sc = (p % 3 == 0) ? SCALE : 1.0f;
  float col[32];
  #pragma unroll
  for (int e = 0; e < 32; ++e) col[e] = w1[e * 64 + d];
  for (int c = 0; c < 32; ++c) {
    float a = 0.f;
    #pragma unroll
    for (int e = 0; e < 32; ++e) a = fmaf(W[c * 32 + e], col[e], a);
    wf[(p * 32 + c) * 64 + d] = a * sc;
  }
  if (d < 32) {
    float a = pw.b[p][d];
    #pragma unroll
    for (int e = 0; e < 32; ++e) a = fmaf(W[d * 32 + e], b1[e], a);
    bfv[p * 32 + d] = a * sc;
  }
}

// ---- qkv[blk][bt][h][m][n][8] = wf[p] * x[b,:,t,n] + bfv[p] ----
__global__ void __launch_bounds__(256) k_qkv(const float* __restrict__ x, const float* __restrict__ wf,
                      const float* __restrict__ bfv, float* __restrict__ qkv) {
  int p     = blockIdx.x;     // 0..5 (blk*3 + m)
  int chunk = blockIdx.y;     // 0..1
  int bt    = blockIdx.z;     // 0..95
  int n = chunk * 256 + threadIdx.x;
  int b = bt / 12, t = bt % 12;
  const float* W = wf + p * 2048;
  float acc[32];
  #pragma unroll
  for (int c = 0; c < 32; ++c) acc[c] = bfv[p * 32 + c];
  const float* xp = x + ((size_t)(b * 64) * 12 + t) * 512 + n;
  for (int d = 0; d < 64; ++d) {
    float xd = xp[(size_t)d * 6144];
    #pragma unroll
    for (int c = 0; c < 32; ++c) acc[c] = fmaf(W[c * 64 + d], xd, acc[c]);
  }
  int blk = p / 3, m = p % 3;
  #pragma unroll
  for (int h = 0; h < 4; ++h) {
    size_t base = (((((size_t)blk * 96 + bt) * 4 + h) * 3 + m) * 512 + n) * 8;
    *(float4*)(qkv + base)     = make_float4(acc[h*8+0], acc[h*8+1], acc[h*8+2], acc[h*8+3]);
    *(float4*)(qkv + base + 4) = make_float4(acc[h*8+4], acc[h*8+5], acc[h*8+6], acc[h*8+7]);
  }
}

// ---- attention, both blocks in one grid: (h=4, bt=96, blk=2), 512 thr = 1 q-row each ----
// single pass (no max subtraction; SCALE pre-folded into q weights)
__global__ void __launch_bounds__(512) k_attn(const float* __restrict__ qkv,
                                              const unsigned* __restrict__ mbw,
                                              float* __restrict__ obuf) {
  __shared__ float Ks[512][8];
  __shared__ float Vs[512][8];
  int h   = blockIdx.x;   // 0..3
  int bt  = blockIdx.y;   // 0..95
  int blk = blockIdx.z;   // 0: plain, 1: geo(masked)
  int n   = threadIdx.x;  // 0..511
  size_t base = ((((size_t)blk * 96 + bt) * 4 + h) * 3) * 4096;
  const float* Q = qkv + base;
  const float* K = Q + 4096;
  const float* V = Q + 8192;
  *(float4*)&Ks[n][0] = *(const float4*)(K + (size_t)n * 8);
  *(float4*)&Ks[n][4] = *(const float4*)(K + (size_t)n * 8 + 4);
  *(float4*)&Vs[n][0] = *(const float4*)(V + (size_t)n * 8);
  *(float4*)&Vs[n][4] = *(const float4*)(V + (size_t)n * 8 + 4);
  __syncthreads();
  float4 q0 = *(const float4*)(Q + (size_t)n * 8);
  float4 q1 = *(const float4*)(Q + (size_t)n * 8 + 4);

  float l = 0.f;
  float a0=0,a1=0,a2=0,a3=0,a4=0,a5=0,a6=0,a7=0;
  if (blk == 0) {
    #pragma unroll 4
    for (int j = 0; j < 512; ++j) {
      float4 k0 = *(float4*)&Ks[j][0];
      float4 k1 = *(float4*)&Ks[j][4];
      float s = q0.x*k0.x + q0.y*k0.y + q0.z*k0.z + q0.w*k0.w
              + q1.x*k1.x + q1.y*k1.y + q1.z*k1.z + q1.w*k1.w;
      float p = __expf(s);
      l += p;
      float4 v0 = *(float4*)&Vs[j][0];
      float4 v1 = *(float4*)&Vs[j][4];
      a0 = fmaf(p, v0.x, a0); a1 = fmaf(p, v0.y, a1);
      a2 = fmaf(p, v0.z, a2); a3 = fmaf(p, v0.w, a3);
      a4 = fmaf(p, v1.x, a4); a5 = fmaf(p, v1.y, a5);
      a6 = fmaf(p, v1.z, a6); a7 = fmaf(p, v1.w, a7);
    }
  } else {
    const unsigned* mrow = mbw + (n << 4);
    for (int w = 0; w < 16; ++w) {
      unsigned mw = mrow[w];
      #pragma unroll 8
      for (int jj = 0; jj < 32; ++jj) {
        int j = w * 32 + jj;
        float4 k0 = *(float4*)&Ks[j][0];
        float4 k1 = *(float4*)&Ks[j][4];
        float s = q0.x*k0.x + q0.y*k0.y + q0.z*k0.z + q0.w*k0.w
                + q1.x*k1.x + q1.y*k1.y + q1.z*k1.z + q1.w*k1.w;
        if ((mw >> jj) & 1u) s = -3.0e38f;
        float p = __expf(s);
        l += p;
        float4 v0 = *(float4*)&Vs[j][0];
        float4 v1 = *(float4*)&Vs[j][4];
        a0 = fmaf(p, v0.x, a0); a1 = fmaf(p, v0.y, a1);
        a2 = fmaf(p, v0.z, a2); a3 = fmaf(p, v0.w, a3);
        a4 = fmaf(p, v1.x, a4); a5 = fmaf(p, v1.y, a5);
        a6 = fmaf(p, v1.z, a6); a7 = fmaf(p, v1.w, a7);
      }
    }
  }
  float inv = 1.0f / l;
  int b = bt / 12, t = bt - b * 12;
  int g = (h * 12 + t) * 128 + (n >> 2);
  float* ob = obuf + (size_t)blk * 1572864 + ((size_t)b * 6144 + g) * 32 + ((n & 3) << 3);
  *(float4*)ob       = make_float4(a0*inv, a1*inv, a2*inv, a3*inv);
  *(float4*)(ob + 4) = make_float4(a4*inv, a5*inv, a6*inv, a7*inv);
}

// ---- epilogue with LDS transpose: out[b][c][t'][n'] = relu(obuf[..] + x[..]) ----
__global__ void __launch_bounds__(256) k_out(const float* __restrict__ x, const float* __restrict__ obuf,
                     float* __restrict__ out) {
  __shared__ float tile[64][65];
  int nc = blockIdx.x;   // 0..7  (n' chunk of 64)
  int tq = blockIdx.y;   // 0..11 (t')
  int b  = blockIdx.z;   // 0..7
  int n0 = nc * 64;
  #pragma unroll
  for (int it = 0; it < 16; ++it) {
    int i = it * 256 + threadIdx.x;
    int nl = i >> 6, c = i & 63;
    int sel = c >> 5;
    tile[nl][c] = obuf[(size_t)sel * 1572864 +
                       ((size_t)b * 6144 + (size_t)(n0 + nl) * 12 + tq) * 32 + (c & 31)];
  }
  __syncthreads();
  #pragma unroll
  for (int it = 0; it < 16; ++it) {
    int i = it * 256 + threadIdx.x;
    int c = i >> 6, nl = i & 63;
    size_t oi = ((size_t)(b * 64 + c) * 12 + tq) * 512 + n0 + nl;
    out[oi] = fmaxf(tile[nl][c] + x[oi], 0.f);
  }
}

extern "C" void kernel_launch(void* const* d_in, const int* in_sizes, int n_in,
                              void* d_out, int out_size, void* d_ws, size_t ws_size,
                              hipStream_t stream) {
  const float* x        = (const float*)d_in[0];
  const int*   geo_mask = (const int*)d_in[1];
  const float* w_proj1  = (const float*)d_in[2];
  const float* b_proj1  = (const float*)d_in[3];
  ProjW pw;
  // blk 0 = plain (x_v), blk 1 = geo (x_geo_v); m: 0=q,1=k,2=v
  pw.w[0] = (const float*)d_in[10]; pw.b[0] = (const float*)d_in[11];  // wq, bq
  pw.w[1] = (const float*)d_in[12]; pw.b[1] = (const float*)d_in[13];  // wk, bk
  pw.w[2] = (const float*)d_in[14]; pw.b[2] = (const float*)d_in[15];  // wv, bv
  pw.w[3] = (const float*)d_in[4];  pw.b[3] = (const float*)d_in[5];   // wgq, bgq
  pw.w[4] = (const float*)d_in[6];  pw.b[4] = (const float*)d_in[7];   // wgk, bgk
  pw.w[5] = (const float*)d_in[8];  pw.b[5] = (const float*)d_in[9];   // wgv, bgv
  float* out = (float*)d_out;

  float* ws = (float*)d_ws;
  float* qkv  = ws;                       // [2][96][4][3][512][8]  = 9,437,184
  float* obuf = ws + 9437184;             // [2][8][512][12][32]    = 3,145,728
  float* wf   = ws + 12582912;            // [6][32][64]            = 12,288
  float* bfv  = ws + 12595200;            // [6][32]                = 192
  unsigned* mbw = (unsigned*)(ws + 12595392);  // [512][16] u32

  k_pack_mask<<<32, 256, 0, stream>>>(geo_mask, mbw);
  k_wfuse<<<6, 64, 0, stream>>>(pw, w_proj1, b_proj1, wf, bfv);
  k_qkv<<<dim3(6, 2, 96), 256, 0, stream>>>(x, wf, bfv, qkv);
  k_attn<<<dim3(4, 96, 2), 512, 0, stream>>>(qkv, mbw, obuf);
  k_out<<<dim3(8, 12, 8), 256, 0, stream>>>(x, obuf, out);
}

// Round 3
// 256.993 us; speedup vs baseline: 1.7603x; 1.1517x over previous
//
#include <hip/hip_runtime.h>
#include <hip/hip_bf16.h>

typedef __attribute__((ext_vector_type(4))) short bf16x4;
typedef __attribute__((ext_vector_type(16))) float f32x16;

#define SCALE 0.35355339059327373f
#define LOG2E 1.4426950408889634f

struct ProjW { const float* w[6]; const float* b[6]; };

template<typename T, typename F>
__device__ inline T bcast(F f) { union { F a; T b; } u; u.a = f; return u.b; }

__device__ inline unsigned pk2(float a, float b) {
  __hip_bfloat162 h = __float22bfloat162_rn(make_float2(a, b));
  return *(unsigned*)&h;
}

// ---- pack geo_mask [512][512] int -> bitmask [512][16] u32 ----
__global__ void k_pack_mask(const int* __restrict__ mask, unsigned* __restrict__ mbw) {
  int w = blockIdx.x * 256 + threadIdx.x;   // 0..8191
  int n = w >> 4, wi = w & 15;
  const int* mp = mask + n * 512 + wi * 32;
  unsigned bits = 0u;
  #pragma unroll
  for (int j = 0; j < 32; ++j) bits |= (mp[j] != 0) ? (1u << j) : 0u;
  mbw[w] = bits;
}

// ---- fused weights, transposed: wfT[p][64 d][32 c] = (W_p*W1)^T ; bfv[p][32] ----
__global__ void k_wfuse(ProjW pw, const float* __restrict__ w1, const float* __restrict__ b1,
                        float* __restrict__ wfT, float* __restrict__ bfv) {
  int p = blockIdx.x;       // 0..5
  int d = threadIdx.x;      // 0..63
  const float* W = pw.w[p];
  float sc = (p % 3 == 0) ? SCALE * LOG2E : 1.0f;   // fold softmax scale + log2e into q
  float col[32];
  #pragma unroll
  for (int e = 0; e < 32; ++e) col[e] = w1[e * 64 + d];
  for (int c = 0; c < 32; ++c) {
    float a = 0.f;
    #pragma unroll
    for (int e = 0; e < 32; ++e) a = fmaf(W[c * 32 + e], col[e], a);
    wfT[(p * 64 + d) * 32 + c] = a * sc;
  }
  if (d < 32) {
    float a = pw.b[p][d];
    #pragma unroll
    for (int e = 0; e < 32; ++e) a = fmaf(W[d * 32 + e], b1[e], a);
    bfv[p * 32 + d] = a * sc;
  }
}

// ---- all 6 projections, x read once; bf16 outputs:
// Qb/Kb: [blk][bt][h][n][8]  (row-major rows of 8)
// Vt:    [blk][bt][h][8][512] (transposed)
__global__ void __launch_bounds__(128) k_qkv(const float* __restrict__ x,
    const float* __restrict__ wfT, const float* __restrict__ bfv,
    ushort* __restrict__ Qb, ushort* __restrict__ Kb, ushort* __restrict__ Vt) {
  int bt = blockIdx.x;   // 0..95
  int ch = blockIdx.y;   // 0..3
  int n = ch * 128 + threadIdx.x;
  int b = bt / 12, t = bt - b * 12;
  const float* xp = x + ((size_t)b * 64 * 12 + t) * 512 + n;
  float xd[64];
  #pragma unroll
  for (int d = 0; d < 64; ++d) xd[d] = xp[(size_t)d * 6144];
  for (int p = 0; p < 6; ++p) {
    const float* W = wfT + p * 2048;
    float acc[32];
    #pragma unroll
    for (int c = 0; c < 32; ++c) acc[c] = bfv[p * 32 + c];
    #pragma unroll 4
    for (int d = 0; d < 64; ++d) {
      float xv = xd[d];
      #pragma unroll
      for (int c = 0; c < 32; ++c) acc[c] = fmaf(W[d * 32 + c], xv, acc[c]);
    }
    int blk = p / 3, m = p - blk * 3;
    if (m < 2) {
      ushort* dst = (m == 0) ? Qb : Kb;
      #pragma unroll
      for (int h = 0; h < 4; ++h) {
        size_t inst = ((size_t)blk * 96 + bt) * 4 + h;
        uint4 u;
        u.x = pk2(acc[h*8+0], acc[h*8+1]);
        u.y = pk2(acc[h*8+2], acc[h*8+3]);
        u.z = pk2(acc[h*8+4], acc[h*8+5]);
        u.w = pk2(acc[h*8+6], acc[h*8+7]);
        *(uint4*)(dst + (inst * 512 + n) * 8) = u;
      }
    } else {
      #pragma unroll
      for (int h = 0; h < 4; ++h) {
        size_t inst = ((size_t)blk * 96 + bt) * 4 + h;
        #pragma unroll
        for (int dd = 0; dd < 8; ++dd) {
          __hip_bfloat16 hb = __float2bfloat16(acc[h*8+dd]);
          Vt[(inst * 8 + dd) * 512 + n] = *(ushort*)&hb;
        }
      }
    }
  }
}

// ---- MFMA attention: grid (h=4, bt=96, blk=2), 512 threads = 8 waves, 64 q-rows/wave ----
__global__ void __launch_bounds__(512) k_attn(const ushort* __restrict__ Qb,
    const ushort* __restrict__ Kb, const ushort* __restrict__ Vt,
    const unsigned* __restrict__ mbw, float* __restrict__ obuf) {
  __shared__ __align__(16) ushort Kl[512 * 12];   // K rows padded 8->12 (bank spread)
  __shared__ __align__(16) ushort Vl[9 * 520];    // V^T rows 0-7 + ones row 8, stride 520
  int h = blockIdx.x, bt = blockIdx.y, blk = blockIdx.z;
  int tid = threadIdx.x;
  size_t inst = ((size_t)blk * 96 + bt) * 4 + h;

  { // stage K: row tid (8 bf16 = 16B) -> Kl[tid*12 ..]
    uint4 kr = ((const uint4*)(Kb + inst * 4096))[tid];
    *(uint2*)&Kl[tid * 12]     = make_uint2(kr.x, kr.y);
    *(uint2*)&Kl[tid * 12 + 4] = make_uint2(kr.z, kr.w);
  }
  { // stage V^T + ones row
    const ushort* vp = Vt + inst * 4096;
    #pragma unroll
    for (int d = 0; d < 8; ++d) Vl[d * 520 + tid] = vp[d * 512 + tid];
    Vl[8 * 520 + tid] = 0x3F80;   // bf16 1.0
  }
  __syncthreads();

  int lane = tid & 63, lo = lane & 31, hi = lane >> 5, w = tid >> 6;
  int qbase = w * 64;

  // Q fragments (B-operand of QK): lane holds Q[q][4*hi + i]
  bf16x4 qf[2];
  #pragma unroll
  for (int s = 0; s < 2; ++s) {
    int q = qbase + s * 32 + lo;
    qf[s] = bcast<bf16x4>(*(const uint2*)(Qb + inst * 4096 + q * 8 + hi * 4));
  }

  f32x16 acc[2], zc;
  #pragma unroll
  for (int i = 0; i < 16; ++i) { acc[0][i] = 0.f; acc[1][i] = 0.f; zc[i] = 0.f; }

  for (int t16 = 0; t16 < 16; ++t16) {
    // K fragment (A-operand): lane holds K[t16*32+lo][4*hi + i]
    bf16x4 kf = bcast<bf16x4>(*(const uint2*)&Kl[(t16 * 32 + lo) * 12 + 4 * hi]);
    // V^T fragments (A-operand of AV): lane holds V^T[lo][kv = t16*32 + 8c + 4hi + i]
    bf16x4 vf[4];
    int vrow = (lo < 8 ? lo : 8) * 520 + t16 * 32 + 4 * hi;
    #pragma unroll
    for (int c = 0; c < 4; ++c) {
      uint2 vv = *(const uint2*)&Vl[vrow + 8 * c];
      if (lo > 8) { vv.x = 0u; vv.y = 0u; }   // rows 9..31 of A are zero
      vf[c] = bcast<bf16x4>(vv);
    }
    #pragma unroll
    for (int s = 0; s < 2; ++s) {
      // S^T tile = K · Q^T : D[kv][q], lane = q-col, regs = kv-rows
      f32x16 st = __builtin_amdgcn_mfma_f32_32x32x8bf16_1k(kf, qf[s], zc, 0, 0, 0);
      unsigned mwh = 0u;
      if (blk == 1) {
        int q = qbase + s * 32 + lo;
        mwh = mbw[q * 16 + t16] >> (4 * hi);
      }
      unsigned u[8];
      #pragma unroll
      for (int j = 0; j < 8; ++j) {
        int r0 = 2 * j, r1 = 2 * j + 1;
        float p0 = exp2f(st[r0]);
        float p1 = exp2f(st[r1]);
        if (blk == 1) {
          int c0 = (r0 & 3) + 8 * (r0 >> 2);
          int c1 = (r1 & 3) + 8 * (r1 >> 2);
          if ((mwh >> c0) & 1u) p0 = 0.f;
          if ((mwh >> c1) & 1u) p1 = 0.f;
        }
        u[j] = pk2(p0, p1);
      }
      // O^T += V^T · P^T in 4 chunks of 8 kv; D regs 4c..4c+3 are B elems 0..3 in-lane
      #pragma unroll
      for (int c = 0; c < 4; ++c) {
        uint2 pu = make_uint2(u[2 * c], u[2 * c + 1]);
        acc[s] = __builtin_amdgcn_mfma_f32_32x32x8bf16_1k(vf[c], bcast<bf16x4>(pu), acc[s], 0, 0, 0);
      }
    }
  }

  // epilogue: lane holds O^T[d = {0..3}+4hi][q], l = acc[4] on hi=0 lanes
  int b = bt / 12, t = bt - b * 12;
  #pragma unroll
  for (int s = 0; s < 2; ++s) {
    float l = __shfl(acc[s][4], lo);
    float inv = __builtin_amdgcn_rcpf(l);
    int q = qbase + s * 32 + lo;
    int g = (h * 12 + t) * 128 + (q >> 2);
    float* ob = obuf + (size_t)blk * 1572864 + ((size_t)b * 6144 + g) * 32 + (q & 3) * 8 + 4 * hi;
    *(float4*)ob = make_float4(acc[s][0] * inv, acc[s][1] * inv, acc[s][2] * inv, acc[s][3] * inv);
  }
}

// ---- epilogue with LDS transpose: out[b][c][t'][n'] = relu(obuf[..] + x[..]) ----
__global__ void __launch_bounds__(256) k_out(const float* __restrict__ x, const float* __restrict__ obuf,
                     float* __restrict__ out) {
  __shared__ float tile[64][65];
  int nc = blockIdx.x;   // 0..7
  int tq = blockIdx.y;   // 0..11
  int b  = blockIdx.z;   // 0..7
  int n0 = nc * 64;
  #pragma unroll
  for (int it = 0; it < 16; ++it) {
    int i = it * 256 + threadIdx.x;
    int nl = i >> 6, c = i & 63;
    int sel = c >> 5;
    tile[nl][c] = obuf[(size_t)sel * 1572864 +
                       ((size_t)b * 6144 + (size_t)(n0 + nl) * 12 + tq) * 32 + (c & 31)];
  }
  __syncthreads();
  #pragma unroll
  for (int it = 0; it < 16; ++it) {
    int i = it * 256 + threadIdx.x;
    int c = i >> 6, nl = i & 63;
    size_t oi = ((size_t)(b * 64 + c) * 12 + tq) * 512 + n0 + nl;
    out[oi] = fmaxf(tile[nl][c] + x[oi], 0.f);
  }
}

extern "C" void kernel_launch(void* const* d_in, const int* in_sizes, int n_in,
                              void* d_out, int out_size, void* d_ws, size_t ws_size,
                              hipStream_t stream) {
  const float* x        = (const float*)d_in[0];
  const int*   geo_mask = (const int*)d_in[1];
  const float* w_proj1  = (const float*)d_in[2];
  const float* b_proj1  = (const float*)d_in[3];
  ProjW pw;
  // blk 0 = plain (x_v), blk 1 = geo (x_geo_v); m: 0=q,1=k,2=v
  pw.w[0] = (const float*)d_in[10]; pw.b[0] = (const float*)d_in[11];  // wq, bq
  pw.w[1] = (const float*)d_in[12]; pw.b[1] = (const float*)d_in[13];  // wk, bk
  pw.w[2] = (const float*)d_in[14]; pw.b[2] = (const float*)d_in[15];  // wv, bv
  pw.w[3] = (const float*)d_in[4];  pw.b[3] = (const float*)d_in[5];   // wgq, bgq
  pw.w[4] = (const float*)d_in[6];  pw.b[4] = (const float*)d_in[7];   // wgk, bgk
  pw.w[5] = (const float*)d_in[8];  pw.b[5] = (const float*)d_in[9];   // wgv, bgv
  float* out = (float*)d_out;

  float* ws = (float*)d_ws;
  float* obuf = ws;                               // [2][8][512][12][32]   = 3,145,728 f32
  float* wfT  = ws + 3145728;                     // [6][64][32]           = 12,288 f32
  float* bfv  = ws + 3158016;                     // [6][32]               = 192 f32
  unsigned* mbw = (unsigned*)(ws + 3158208);      // [512][16] u32         = 8,192 u32
  ushort* Qb = (ushort*)(ws + 3166400);           // [2][96][4][512][8]    = 3,145,728 u16
  ushort* Kb = (ushort*)(ws + 4739264);           // same
  ushort* Vt = (ushort*)(ws + 6312128);           // [2][96][4][8][512]

  k_pack_mask<<<32, 256, 0, stream>>>(geo_mask, mbw);
  k_wfuse<<<6, 64, 0, stream>>>(pw, w_proj1, b_proj1, wfT, bfv);
  k_qkv<<<dim3(96, 4), 128, 0, stream>>>(x, wfT, bfv, Qb, Kb, Vt);
  k_attn<<<dim3(4, 96, 2), 512, 0, stream>>>(Qb, Kb, Vt, mbw, obuf);
  k_out<<<dim3(8, 12, 8), 256, 0, stream>>>(x, obuf, out);
}

// Round 4
// 245.374 us; speedup vs baseline: 1.8436x; 1.0474x over previous
//
#include <hip/hip_runtime.h>
#include <hip/hip_bf16.h>

typedef __attribute__((ext_vector_type(4))) short bf16x4;
typedef __attribute__((ext_vector_type(16))) float f32x16;

#define SCALE 0.35355339059327373f
#define LOG2E 1.4426950408889634f

struct ProjW { const float* w[6]; const float* b[6]; };

template<typename T, typename F>
__device__ inline T bcast(F f) { union { F a; T b; } u; u.a = f; return u.b; }

__device__ inline unsigned pk2(float a, float b) {
  __hip_bfloat162 h = __float22bfloat162_rn(make_float2(a, b));
  return *(unsigned*)&h;
}

// ---- pack geo_mask [512][512] int -> bitmask [512][16] u32 ----
__global__ void k_pack_mask(const int* __restrict__ mask, unsigned* __restrict__ mbw) {
  int w = blockIdx.x * 256 + threadIdx.x;   // 0..8191
  int n = w >> 4, wi = w & 15;
  const int* mp = mask + n * 512 + wi * 32;
  unsigned bits = 0u;
  #pragma unroll
  for (int j = 0; j < 32; ++j) bits |= (mp[j] != 0) ? (1u << j) : 0u;
  mbw[w] = bits;
}

// ---- fused weights, transposed: wfT[p][64 d][32 c] = (W_p*W1)^T ; bfv[p][32] ----
__global__ void k_wfuse(ProjW pw, const float* __restrict__ w1, const float* __restrict__ b1,
                        float* __restrict__ wfT, float* __restrict__ bfv) {
  int p = blockIdx.x;       // 0..5
  int d = threadIdx.x;      // 0..63
  const float* W = pw.w[p];
  float sc = (p % 3 == 0) ? SCALE * LOG2E : 1.0f;   // fold softmax scale + log2e into q
  float col[32];
  #pragma unroll
  for (int e = 0; e < 32; ++e) col[e] = w1[e * 64 + d];
  for (int c = 0; c < 32; ++c) {
    float a = 0.f;
    #pragma unroll
    for (int e = 0; e < 32; ++e) a = fmaf(W[c * 32 + e], col[e], a);
    wfT[(p * 64 + d) * 32 + c] = a * sc;
  }
  if (d < 32) {
    float a = pw.b[p][d];
    #pragma unroll
    for (int e = 0; e < 32; ++e) a = fmaf(W[d * 32 + e], b1[e], a);
    bfv[p * 32 + d] = a * sc;
  }
}

// ---- all 6 projections; block = 384 thr (wave = one p, 64 n); x staged in LDS ----
// Qb/Kb: [blk][bt][h][n][8]  (row-major rows of 8)
// Vt:    [blk][bt][h][8][512] (transposed)
__global__ void __launch_bounds__(384) k_qkv(const float* __restrict__ x,
    const float* __restrict__ wfT, const float* __restrict__ bfv,
    ushort* __restrict__ Qb, ushort* __restrict__ Kb, ushort* __restrict__ Vt) {
  __shared__ float xs[64 * 64];   // [d][nl], 16 KB
  int bt = blockIdx.x;   // 0..95
  int ch = blockIdx.y;   // 0..7
  int tid = threadIdx.x;
  int n0 = ch * 64;
  int b = bt / 12, t = bt - b * 12;
  // stage x[64 d][64 n] -> LDS (coalesced along n)
  const float* xb = x + ((size_t)b * 64 * 12 + t) * 512 + n0;
  for (int i = tid; i < 4096; i += 384) {
    int d = i >> 6, nl2 = i & 63;
    xs[i] = xb[(size_t)d * 6144 + nl2];
  }
  __syncthreads();

  int p = tid >> 6;      // 0..5, wave-uniform
  int nl = tid & 63;
  int n = n0 + nl;
  const float* W = wfT + p * 2048;
  float acc[32];
  #pragma unroll
  for (int c = 0; c < 32; ++c) acc[c] = bfv[p * 32 + c];
  #pragma unroll 4
  for (int d = 0; d < 64; ++d) {
    float xv = xs[d * 64 + nl];
    #pragma unroll
    for (int c = 0; c < 32; ++c) acc[c] = fmaf(W[d * 32 + c], xv, acc[c]);
  }

  int blk = p / 3, m = p - blk * 3;
  if (m < 2) {
    ushort* dst = (m == 0) ? Qb : Kb;
    #pragma unroll
    for (int h = 0; h < 4; ++h) {
      size_t inst = ((size_t)blk * 96 + bt) * 4 + h;
      uint4 u;
      u.x = pk2(acc[h*8+0], acc[h*8+1]);
      u.y = pk2(acc[h*8+2], acc[h*8+3]);
      u.z = pk2(acc[h*8+4], acc[h*8+5]);
      u.w = pk2(acc[h*8+6], acc[h*8+7]);
      *(uint4*)(dst + (inst * 512 + n) * 8) = u;
    }
  } else {
    #pragma unroll
    for (int h = 0; h < 4; ++h) {
      size_t inst = ((size_t)blk * 96 + bt) * 4 + h;
      #pragma unroll
      for (int dd = 0; dd < 8; ++dd) {
        __hip_bfloat16 hb = __float2bfloat16(acc[h*8+dd]);
        Vt[(inst * 8 + dd) * 512 + n] = *(ushort*)&hb;
      }
    }
  }
}

// ---- MFMA attention: grid (h=4, bt=96, blk=2), 512 threads = 8 waves, 64 q-rows/wave ----
__global__ void __launch_bounds__(512) k_attn(const ushort* __restrict__ Qb,
    const ushort* __restrict__ Kb, const ushort* __restrict__ Vt,
    const unsigned* __restrict__ mbw, float* __restrict__ obuf) {
  __shared__ __align__(16) ushort Kl[512 * 12];   // K rows padded 8->12 (bank spread)
  __shared__ __align__(16) ushort Vl[9 * 520];    // V^T rows 0-7 + ones row 8, stride 520
  int h = blockIdx.x, bt = blockIdx.y, blk = blockIdx.z;
  int tid = threadIdx.x;
  size_t inst = ((size_t)blk * 96 + bt) * 4 + h;

  { // stage K: row tid (8 bf16 = 16B) -> Kl[tid*12 ..]
    uint4 kr = ((const uint4*)(Kb + inst * 4096))[tid];
    *(uint2*)&Kl[tid * 12]     = make_uint2(kr.x, kr.y);
    *(uint2*)&Kl[tid * 12 + 4] = make_uint2(kr.z, kr.w);
  }
  { // stage V^T + ones row
    const ushort* vp = Vt + inst * 4096;
    #pragma unroll
    for (int d = 0; d < 8; ++d) Vl[d * 520 + tid] = vp[d * 512 + tid];
    Vl[8 * 520 + tid] = 0x3F80;   // bf16 1.0
  }
  __syncthreads();

  int lane = tid & 63, lo = lane & 31, hi = lane >> 5, w = tid >> 6;
  int qbase = w * 64;

  // Q fragments (B-operand of QK): lane holds Q[q][4*hi + i]
  bf16x4 qf[2];
  #pragma unroll
  for (int s = 0; s < 2; ++s) {
    int q = qbase + s * 32 + lo;
    qf[s] = bcast<bf16x4>(*(const uint2*)(Qb + inst * 4096 + q * 8 + hi * 4));
  }

  f32x16 acc[2], zc;
  #pragma unroll
  for (int i = 0; i < 16; ++i) { acc[0][i] = 0.f; acc[1][i] = 0.f; zc[i] = 0.f; }

  for (int t16 = 0; t16 < 16; ++t16) {
    // K fragment (A-operand): lane holds K[t16*32+lo][4*hi + i]
    bf16x4 kf = bcast<bf16x4>(*(const uint2*)&Kl[(t16 * 32 + lo) * 12 + 4 * hi]);
    // V^T fragments (A-operand of AV): lane holds V^T[lo][kv = t16*32 + 8c + 4hi + i]
    bf16x4 vf[4];
    int vrow = (lo < 8 ? lo : 8) * 520 + t16 * 32 + 4 * hi;
    #pragma unroll
    for (int c = 0; c < 4; ++c) {
      uint2 vv = *(const uint2*)&Vl[vrow + 8 * c];
      if (lo > 8) { vv.x = 0u; vv.y = 0u; }   // rows 9..31 of A are zero
      vf[c] = bcast<bf16x4>(vv);
    }
    #pragma unroll
    for (int s = 0; s < 2; ++s) {
      // S^T tile = K · Q^T : D[kv][q], lane = q-col, regs = kv-rows
      f32x16 st = __builtin_amdgcn_mfma_f32_32x32x8bf16_1k(kf, qf[s], zc, 0, 0, 0);
      unsigned mwh = 0u;
      if (blk == 1) {
        int q = qbase + s * 32 + lo;
        mwh = mbw[q * 16 + t16] >> (4 * hi);
      }
      unsigned u[8];
      #pragma unroll
      for (int j = 0; j < 8; ++j) {
        int r0 = 2 * j, r1 = 2 * j + 1;
        float p0 = exp2f(st[r0]);
        float p1 = exp2f(st[r1]);
        if (blk == 1) {
          int c0 = (r0 & 3) + 8 * (r0 >> 2);
          int c1 = (r1 & 3) + 8 * (r1 >> 2);
          if ((mwh >> c0) & 1u) p0 = 0.f;
          if ((mwh >> c1) & 1u) p1 = 0.f;
        }
        u[j] = pk2(p0, p1);
      }
      // O^T += V^T · P^T in 4 chunks of 8 kv; D regs 4c..4c+3 are B elems 0..3 in-lane
      #pragma unroll
      for (int c = 0; c < 4; ++c) {
        uint2 pu = make_uint2(u[2 * c], u[2 * c + 1]);
        acc[s] = __builtin_amdgcn_mfma_f32_32x32x8bf16_1k(vf[c], bcast<bf16x4>(pu), acc[s], 0, 0, 0);
      }
    }
  }

  // epilogue: lane holds O^T[d = {0..3}+4hi][q], l = acc[4] on hi=0 lanes
  int b = bt / 12, t = bt - b * 12;
  #pragma unroll
  for (int s = 0; s < 2; ++s) {
    float l = __shfl(acc[s][4], lo);
    float inv = __builtin_amdgcn_rcpf(l);
    int q = qbase + s * 32 + lo;
    int g = (h * 12 + t) * 128 + (q >> 2);
    float* ob = obuf + (size_t)blk * 1572864 + ((size_t)b * 6144 + g) * 32 + (q & 3) * 8 + 4 * hi;
    *(float4*)ob = make_float4(acc[s][0] * inv, acc[s][1] * inv, acc[s][2] * inv, acc[s][3] * inv);
  }
}

// ---- epilogue with LDS transpose: out[b][c][t'][n'] = relu(obuf[..] + x[..]) ----
__global__ void __launch_bounds__(256) k_out(const float* __restrict__ x, const float* __restrict__ obuf,
                     float* __restrict__ out) {
  __shared__ float tile[64][65];
  int nc = blockIdx.x;   // 0..7
  int tq = blockIdx.y;   // 0..11
  int b  = blockIdx.z;   // 0..7
  int n0 = nc * 64;
  #pragma unroll
  for (int it = 0; it < 16; ++it) {
    int i = it * 256 + threadIdx.x;
    int nl = i >> 6, c = i & 63;
    int sel = c >> 5;
    tile[nl][c] = obuf[(size_t)sel * 1572864 +
                       ((size_t)b * 6144 + (size_t)(n0 + nl) * 12 + tq) * 32 + (c & 31)];
  }
  __syncthreads();
  #pragma unroll
  for (int it = 0; it < 16; ++it) {
    int i = it * 256 + threadIdx.x;
    int c = i >> 6, nl = i & 63;
    size_t oi = ((size_t)(b * 64 + c) * 12 + tq) * 512 + n0 + nl;
    out[oi] = fmaxf(tile[nl][c] + x[oi], 0.f);
  }
}

extern "C" void kernel_launch(void* const* d_in, const int* in_sizes, int n_in,
                              void* d_out, int out_size, void* d_ws, size_t ws_size,
                              hipStream_t stream) {
  const float* x        = (const float*)d_in[0];
  const int*   geo_mask = (const int*)d_in[1];
  const float* w_proj1  = (const float*)d_in[2];
  const float* b_proj1  = (const float*)d_in[3];
  ProjW pw;
  // blk 0 = plain (x_v), blk 1 = geo (x_geo_v); m: 0=q,1=k,2=v
  pw.w[0] = (const float*)d_in[10]; pw.b[0] = (const float*)d_in[11];  // wq, bq
  pw.w[1] = (const float*)d_in[12]; pw.b[1] = (const float*)d_in[13];  // wk, bk
  pw.w[2] = (const float*)d_in[14]; pw.b[2] = (const float*)d_in[15];  // wv, bv
  pw.w[3] = (const float*)d_in[4];  pw.b[3] = (const float*)d_in[5];   // wgq, bgq
  pw.w[4] = (const float*)d_in[6];  pw.b[4] = (const float*)d_in[7];   // wgk, bgk
  pw.w[5] = (const float*)d_in[8];  pw.b[5] = (const float*)d_in[9];   // wgv, bgv
  float* out = (float*)d_out;

  float* ws = (float*)d_ws;
  float* obuf = ws;                               // [2][8][512][12][32]   = 3,145,728 f32
  float* wfT  = ws + 3145728;                     // [6][64][32]           = 12,288 f32
  float* bfv  = ws + 3158016;                     // [6][32]               = 192 f32
  unsigned* mbw = (unsigned*)(ws + 3158208);      // [512][16] u32         = 8,192 u32
  ushort* Qb = (ushort*)(ws + 3166400);           // [2][96][4][512][8]    = 3,145,728 u16
  ushort* Kb = (ushort*)(ws + 4739264);           // same
  ushort* Vt = (ushort*)(ws + 6312128);           // [2][96][4][8][512]

  k_pack_mask<<<32, 256, 0, stream>>>(geo_mask, mbw);
  k_wfuse<<<6, 64, 0, stream>>>(pw, w_proj1, b_proj1, wfT, bfv);
  k_qkv<<<dim3(96, 8), 384, 0, stream>>>(x, wfT, bfv, Qb, Kb, Vt);
  k_attn<<<dim3(4, 96, 2), 512, 0, stream>>>(Qb, Kb, Vt, mbw, obuf);
  k_out<<<dim3(8, 12, 8), 256, 0, stream>>>(x, obuf, out);
}

// Round 7
// 215.203 us; speedup vs baseline: 2.1021x; 1.1402x over previous
//
#include <hip/hip_runtime.h>
#include <hip/hip_bf16.h>

typedef __attribute__((ext_vector_type(4))) short bf16x4;
typedef __attribute__((ext_vector_type(16))) float f32x16;

#define SCALE 0.35355339059327373f
#define LOG2E 1.4426950408889634f

struct ProjW { const float* w[6]; const float* b[6]; };

template<typename T, typename F>
__device__ inline T bcast(F f) { union { F a; T b; } u; u.a = f; return u.b; }

__device__ inline unsigned pk2(float a, float b) {
  __hip_bfloat162 h = __float22bfloat162_rn(make_float2(a, b));
  return *(unsigned*)&h;
}

// ---- pack geo_mask [512][512] int -> bitmask [512][16] u32 ----
__global__ void k_pack_mask(const int* __restrict__ mask, unsigned* __restrict__ mbw) {
  int w = blockIdx.x * 256 + threadIdx.x;   // 0..8191
  int n = w >> 4, wi = w & 15;
  const int* mp = mask + n * 512 + wi * 32;
  unsigned bits = 0u;
  #pragma unroll
  for (int j = 0; j < 32; ++j) bits |= (mp[j] != 0) ? (1u << j) : 0u;
  mbw[w] = bits;
}

// ---- fused weights, transposed: wfT[p][64 d][32 c] = (W_p*W1)^T ; bfv[p][32] ----
__global__ void k_wfuse(ProjW pw, const float* __restrict__ w1, const float* __restrict__ b1,
                        float* __restrict__ wfT, float* __restrict__ bfv) {
  int p = blockIdx.x;       // 0..5
  int d = threadIdx.x;      // 0..63
  const float* W = pw.w[p];
  float sc = (p % 3 == 0) ? SCALE * LOG2E : 1.0f;   // fold softmax scale + log2e into q
  float col[32];
  #pragma unroll
  for (int e = 0; e < 32; ++e) col[e] = w1[e * 64 + d];
  for (int c = 0; c < 32; ++c) {
    float a = 0.f;
    #pragma unroll
    for (int e = 0; e < 32; ++e) a = fmaf(W[c * 32 + e], col[e], a);
    wfT[(p * 64 + d) * 32 + c] = a * sc;
  }
  if (d < 32) {
    float a = pw.b[p][d];
    #pragma unroll
    for (int e = 0; e < 32; ++e) a = fmaf(W[d * 32 + e], b1[e], a);
    bfv[p * 32 + d] = a * sc;
  }
}

// ---- all 6 projections; block = 384 thr = 6 waves (wave = one p), 128 n per block ----
// W staged in LDS (uniform broadcast reads); x staged as bf16 pairs; 2 n per thread.
// Qb/Kb: [blk][bt][h][n][8]  (row-major rows of 8)
// Vt:    [blk][bt][h][8][512] (transposed)
__global__ void __launch_bounds__(384) k_qkv(const float* __restrict__ x,
    const float* __restrict__ wfT, const float* __restrict__ bfv,
    ushort* __restrict__ Qb, ushort* __restrict__ Kb, ushort* __restrict__ Vt) {
  __shared__ float Wl[12288];        // [6][64][32] fp32, 48 KB
  __shared__ unsigned xs32[4096];    // [64 d][64 n-pairs] bf16x2, 16 KB
  int bt = blockIdx.x;   // 0..95
  int ch = blockIdx.y;   // 0..3
  int tid = threadIdx.x;
  int n0 = ch * 128;
  int b = bt / 12, t = bt - b * 12;
  const float* xb = x + ((size_t)b * 768 + t) * 512 + n0;
  // stage x[64 d][128 n] -> bf16 pairs (coalesced float2 reads)
  for (int i = tid; i < 4096; i += 384) {
    int d = i >> 6, np = i & 63;
    float2 v = *(const float2*)(xb + (size_t)d * 6144 + 2 * np);
    xs32[d * 64 + np] = pk2(v.x, v.y);
  }
  // stage all fused weights
  for (int i = tid; i < 12288; i += 384) Wl[i] = wfT[i];
  __syncthreads();

  int p = tid >> 6;      // 0..5, wave-uniform
  int nl = tid & 63;     // n-pair index; n = n0 + 2*nl {+0,1}
  const float* W = Wl + p * 2048;
  float accA[32], accB[32];
  #pragma unroll
  for (int c = 0; c < 32; ++c) { accA[c] = bfv[p * 32 + c]; accB[c] = accA[c]; }
  #pragma unroll 8
  for (int d = 0; d < 64; ++d) {
    unsigned xu = xs32[d * 64 + nl];
    float xa = __uint_as_float(xu << 16);
    float xbv = __uint_as_float(xu & 0xffff0000u);
    #pragma unroll
    for (int c4 = 0; c4 < 8; ++c4) {
      float4 w = *(const float4*)(W + d * 32 + c4 * 4);
      accA[c4*4+0] = fmaf(w.x, xa, accA[c4*4+0]); accB[c4*4+0] = fmaf(w.x, xbv, accB[c4*4+0]);
      accA[c4*4+1] = fmaf(w.y, xa, accA[c4*4+1]); accB[c4*4+1] = fmaf(w.y, xbv, accB[c4*4+1]);
      accA[c4*4+2] = fmaf(w.z, xa, accA[c4*4+2]); accB[c4*4+2] = fmaf(w.z, xbv, accB[c4*4+2]);
      accA[c4*4+3] = fmaf(w.w, xa, accA[c4*4+3]); accB[c4*4+3] = fmaf(w.w, xbv, accB[c4*4+3]);
    }
  }

  int blk = p / 3, m = p - blk * 3;
  int n = n0 + 2 * nl;
  if (m < 2) {
    ushort* dst = (m == 0) ? Qb : Kb;
    #pragma unroll
    for (int h = 0; h < 4; ++h) {
      size_t inst = ((size_t)blk * 96 + bt) * 4 + h;
      uint4 uA, uB;
      uA.x = pk2(accA[h*8+0], accA[h*8+1]); uA.y = pk2(accA[h*8+2], accA[h*8+3]);
      uA.z = pk2(accA[h*8+4], accA[h*8+5]); uA.w = pk2(accA[h*8+6], accA[h*8+7]);
      uB.x = pk2(accB[h*8+0], accB[h*8+1]); uB.y = pk2(accB[h*8+2], accB[h*8+3]);
      uB.z = pk2(accB[h*8+4], accB[h*8+5]); uB.w = pk2(accB[h*8+6], accB[h*8+7]);
      *(uint4*)(dst + (inst * 512 + n) * 8)     = uA;
      *(uint4*)(dst + (inst * 512 + n + 1) * 8) = uB;
    }
  } else {
    #pragma unroll
    for (int h = 0; h < 4; ++h) {
      size_t inst = ((size_t)blk * 96 + bt) * 4 + h;
      #pragma unroll
      for (int dd = 0; dd < 8; ++dd)
        *(unsigned*)(Vt + (inst * 8 + dd) * 512 + n) = pk2(accA[h*8+dd], accB[h*8+dd]);
    }
  }
}

// ---- MFMA attention: grid (h=4, bt=96, blk=2), 512 threads = 8 waves, 64 q-rows/wave ----
__global__ void __launch_bounds__(512) k_attn(const ushort* __restrict__ Qb,
    const ushort* __restrict__ Kb, const ushort* __restrict__ Vt,
    const unsigned* __restrict__ mbw, float* __restrict__ obuf) {
  __shared__ __align__(16) ushort Kl[512 * 12];   // K rows padded 8->12 (bank spread)
  __shared__ __align__(16) ushort Vl[9 * 520];    // V^T rows 0-7 + ones row 8, stride 520
  int h = blockIdx.x, bt = blockIdx.y, blk = blockIdx.z;
  int tid = threadIdx.x;
  size_t inst = ((size_t)blk * 96 + bt) * 4 + h;

  { // stage K: row tid (8 bf16 = 16B) -> Kl[tid*12 ..]
    uint4 kr = ((const uint4*)(Kb + inst * 4096))[tid];
    *(uint2*)&Kl[tid * 12]     = make_uint2(kr.x, kr.y);
    *(uint2*)&Kl[tid * 12 + 4] = make_uint2(kr.z, kr.w);
  }
  { // stage V^T + ones row
    const ushort* vp = Vt + inst * 4096;
    #pragma unroll
    for (int d = 0; d < 8; ++d) Vl[d * 520 + tid] = vp[d * 512 + tid];
    Vl[8 * 520 + tid] = 0x3F80;   // bf16 1.0
  }
  __syncthreads();

  int lane = tid & 63, lo = lane & 31, hi = lane >> 5, w = tid >> 6;
  int qbase = w * 64;

  // Q fragments (B-operand of QK): lane holds Q[q][4*hi + i]
  bf16x4 qf[2];
  #pragma unroll
  for (int s = 0; s < 2; ++s) {
    int q = qbase + s * 32 + lo;
    qf[s] = bcast<bf16x4>(*(const uint2*)(Qb + inst * 4096 + q * 8 + hi * 4));
  }

  f32x16 acc[2], zc;
  #pragma unroll
  for (int i = 0; i < 16; ++i) { acc[0][i] = 0.f; acc[1][i] = 0.f; zc[i] = 0.f; }

  for (int t16 = 0; t16 < 16; ++t16) {
    // K fragment (A-operand): lane holds K[t16*32+lo][4*hi + i]
    bf16x4 kf = bcast<bf16x4>(*(const uint2*)&Kl[(t16 * 32 + lo) * 12 + 4 * hi]);
    // V^T fragments (A-operand of AV): lane holds V^T[lo][kv = t16*32 + 8c + 4hi + i]
    bf16x4 vf[4];
    int vrow = (lo < 8 ? lo : 8) * 520 + t16 * 32 + 4 * hi;
    #pragma unroll
    for (int c = 0; c < 4; ++c) {
      uint2 vv = *(const uint2*)&Vl[vrow + 8 * c];
      if (lo > 8) { vv.x = 0u; vv.y = 0u; }   // rows 9..31 of A are zero
      vf[c] = bcast<bf16x4>(vv);
    }
    #pragma unroll
    for (int s = 0; s < 2; ++s) {
      // S^T tile = K · Q^T : D[kv][q], lane = q-col, regs = kv-rows
      f32x16 st = __builtin_amdgcn_mfma_f32_32x32x8bf16_1k(kf, qf[s], zc, 0, 0, 0);
      unsigned mwh = 0u;
      if (blk == 1) {
        int q = qbase + s * 32 + lo;
        mwh = mbw[q * 16 + t16] >> (4 * hi);
      }
      unsigned u[8];
      #pragma unroll
      for (int j = 0; j < 8; ++j) {
        int r0 = 2 * j, r1 = 2 * j + 1;
        float p0 = exp2f(st[r0]);
        float p1 = exp2f(st[r1]);
        if (blk == 1) {
          int c0 = (r0 & 3) + 8 * (r0 >> 2);
          int c1 = (r1 & 3) + 8 * (r1 >> 2);
          if ((mwh >> c0) & 1u) p0 = 0.f;
          if ((mwh >> c1) & 1u) p1 = 0.f;
        }
        u[j] = pk2(p0, p1);
      }
      // O^T += V^T · P^T in 4 chunks of 8 kv; D regs 4c..4c+3 are B elems 0..3 in-lane
      #pragma unroll
      for (int c = 0; c < 4; ++c) {
        uint2 pu = make_uint2(u[2 * c], u[2 * c + 1]);
        acc[s] = __builtin_amdgcn_mfma_f32_32x32x8bf16_1k(vf[c], bcast<bf16x4>(pu), acc[s], 0, 0, 0);
      }
    }
  }

  // epilogue: lane holds O^T[d = {0..3}+4hi][q], l = acc[4] on hi=0 lanes
  int b = bt / 12, t = bt - b * 12;
  #pragma unroll
  for (int s = 0; s < 2; ++s) {
    float l = __shfl(acc[s][4], lo);
    float inv = __builtin_amdgcn_rcpf(l);
    int q = qbase + s * 32 + lo;
    int g = (h * 12 + t) * 128 + (q >> 2);
    float* ob = obuf + (size_t)blk * 1572864 + ((size_t)b * 6144 + g) * 32 + (q & 3) * 8 + 4 * hi;
    *(float4*)ob = make_float4(acc[s][0] * inv, acc[s][1] * inv, acc[s][2] * inv, acc[s][3] * inv);
  }
}

// ---- epilogue with LDS transpose: out[b][c][t'][n'] = relu(obuf[..] + x[..]) ----
__global__ void __launch_bounds__(256) k_out(const float* __restrict__ x, const float* __restrict__ obuf,
                     float* __restrict__ out) {
  __shared__ float tile[64][65];
  int nc = blockIdx.x;   // 0..7
  int tq = blockIdx.y;   // 0..11
  int b  = blockIdx.z;   // 0..7
  int n0 = nc * 64;
  #pragma unroll
  for (int it = 0; it < 16; ++it) {
    int i = it * 256 + threadIdx.x;
    int nl = i >> 6, c = i & 63;
    int sel = c >> 5;
    tile[nl][c] = obuf[(size_t)sel * 1572864 +
                       ((size_t)b * 6144 + (size_t)(n0 + nl) * 12 + tq) * 32 + (c & 31)];
  }
  __syncthreads();
  #pragma unroll
  for (int it = 0; it < 16; ++it) {
    int i = it * 256 + threadIdx.x;
    int c = i >> 6, nl = i & 63;
    size_t oi = ((size_t)(b * 64 + c) * 12 + tq) * 512 + n0 + nl;
    out[oi] = fmaxf(tile[nl][c] + x[oi], 0.f);
  }
}

extern "C" void kernel_launch(void* const* d_in, const int* in_sizes, int n_in,
                              void* d_out, int out_size, void* d_ws, size_t ws_size,
                              hipStream_t stream) {
  const float* x        = (const float*)d_in[0];
  const int*   geo_mask = (const int*)d_in[1];
  const float* w_proj1  = (const float*)d_in[2];
  const float* b_proj1  = (const float*)d_in[3];
  ProjW pw;
  // blk 0 = plain (x_v), blk 1 = geo (x_geo_v); m: 0=q,1=k,2=v
  pw.w[0] = (const float*)d_in[10]; pw.b[0] = (const float*)d_in[11];  // wq, bq
  pw.w[1] = (const float*)d_in[12]; pw.b[1] = (const float*)d_in[13];  // wk, bk
  pw.w[2] = (const float*)d_in[14]; pw.b[2] = (const float*)d_in[15];  // wv, bv
  pw.w[3] = (const float*)d_in[4];  pw.b[3] = (const float*)d_in[5];   // wgq, bgq
  pw.w[4] = (const float*)d_in[6];  pw.b[4] = (const float*)d_in[7];   // wgk, bgk
  pw.w[5] = (const float*)d_in[8];  pw.b[5] = (const float*)d_in[9];   // wgv, bgv
  float* out = (float*)d_out;

  float* ws = (float*)d_ws;
  float* obuf = ws;                               // [2][8][512][12][32]   = 3,145,728 f32
  float* wfT  = ws + 3145728;                     // [6][64][32]           = 12,288 f32
  float* bfv  = ws + 3158016;                     // [6][32]               = 192 f32
  unsigned* mbw = (unsigned*)(ws + 3158208);      // [512][16] u32         = 8,192 u32
  ushort* Qb = (ushort*)(ws + 3166400);           // [2][96][4][512][8]    = 3,145,728 u16
  ushort* Kb = (ushort*)(ws + 4739264);           // same
  ushort* Vt = (ushort*)(ws + 6312128);           // [2][96][4][8][512]

  k_pack_mask<<<32, 256, 0, stream>>>(geo_mask, mbw);
  k_wfuse<<<6, 64, 0, stream>>>(pw, w_proj1, b_proj1, wfT, bfv);
  k_qkv<<<dim3(96, 4), 384, 0, stream>>>(x, wfT, bfv, Qb, Kb, Vt);
  k_attn<<<dim3(4, 96, 2), 512, 0, stream>>>(Qb, Kb, Vt, mbw, obuf);
  k_out<<<dim3(8, 12, 8), 256, 0, stream>>>(x, obuf, out);
}

// Round 8
// 189.881 us; speedup vs baseline: 2.3824x; 1.1334x over previous
//
#include <hip/hip_runtime.h>
#include <hip/hip_bf16.h>

typedef __attribute__((ext_vector_type(4))) short bf16x4;
typedef __attribute__((ext_vector_type(16))) float f32x16;

#define SCALE 0.35355339059327373f
#define LOG2E 1.4426950408889634f

struct ProjW { const float* w[6]; const float* b[6]; };

template<typename T, typename F>
__device__ inline T bcast(F f) { union { F a; T b; } u; u.a = f; return u.b; }

__device__ inline unsigned pk2(float a, float b) {
  __hip_bfloat162 h = __float22bfloat162_rn(make_float2(a, b));
  return *(unsigned*)&h;
}

__device__ inline float fast_exp2(float x) {
  float r;
  asm("v_exp_f32 %0, %1" : "=v"(r) : "v"(x));
  return r;
}

// ---- pack geo_mask [512][512] int -> bitmask [512][16] u32 ----
__global__ void k_pack_mask(const int* __restrict__ mask, unsigned* __restrict__ mbw) {
  int w = blockIdx.x * 256 + threadIdx.x;   // 0..8191
  int n = w >> 4, wi = w & 15;
  const int* mp = mask + n * 512 + wi * 32;
  unsigned bits = 0u;
  #pragma unroll
  for (int j = 0; j < 32; ++j) bits |= (mp[j] != 0) ? (1u << j) : 0u;
  mbw[w] = bits;
}

// ---- fused weights, transposed: wfT[p][64 d][32 c] = (W_p*W1)^T ; bfv[p][32] ----
__global__ void k_wfuse(ProjW pw, const float* __restrict__ w1, const float* __restrict__ b1,
                        float* __restrict__ wfT, float* __restrict__ bfv) {
  int p = blockIdx.x;       // 0..5
  int d = threadIdx.x;      // 0..63
  const float* W = pw.w[p];
  float sc = (p % 3 == 0) ? SCALE * LOG2E : 1.0f;   // fold softmax scale + log2e into q
  float col[32];
  #pragma unroll
  for (int e = 0; e < 32; ++e) col[e] = w1[e * 64 + d];
  for (int c = 0; c < 32; ++c) {
    float a = 0.f;
    #pragma unroll
    for (int e = 0; e < 32; ++e) a = fmaf(W[c * 32 + e], col[e], a);
    wfT[(p * 64 + d) * 32 + c] = a * sc;
  }
  if (d < 32) {
    float a = pw.b[p][d];
    #pragma unroll
    for (int e = 0; e < 32; ++e) a = fmaf(W[d * 32 + e], b1[e], a);
    bfv[p * 32 + d] = a * sc;
  }
}

// ---- all 6 projections; block = 384 thr = 6 waves (wave = one p), 128 n per block ----
// W staged in LDS (uniform broadcast reads); x staged as bf16 pairs; 2 n per thread.
// Qb/Kb: [blk][bt][h][n][8]  (row-major rows of 8)
// Vt:    [blk][bt][h][8][512] (transposed)
__global__ void __launch_bounds__(384) k_qkv(const float* __restrict__ x,
    const float* __restrict__ wfT, const float* __restrict__ bfv,
    ushort* __restrict__ Qb, ushort* __restrict__ Kb, ushort* __restrict__ Vt) {
  __shared__ float Wl[12288];        // [6][64][32] fp32, 48 KB
  __shared__ unsigned xs32[4096];    // [64 d][64 n-pairs] bf16x2, 16 KB
  int bt = blockIdx.x;   // 0..95
  int ch = blockIdx.y;   // 0..3
  int tid = threadIdx.x;
  int n0 = ch * 128;
  int b = bt / 12, t = bt - b * 12;
  const float* xb = x + ((size_t)b * 768 + t) * 512 + n0;
  // stage x[64 d][128 n] -> bf16 pairs (coalesced float2 reads)
  for (int i = tid; i < 4096; i += 384) {
    int d = i >> 6, np = i & 63;
    float2 v = *(const float2*)(xb + (size_t)d * 6144 + 2 * np);
    xs32[d * 64 + np] = pk2(v.x, v.y);
  }
  // stage all fused weights
  for (int i = tid; i < 12288; i += 384) Wl[i] = wfT[i];
  __syncthreads();

  int p = tid >> 6;      // 0..5, wave-uniform
  int nl = tid & 63;     // n-pair index; n = n0 + 2*nl {+0,1}
  const float* W = Wl + p * 2048;
  float accA[32], accB[32];
  #pragma unroll
  for (int c = 0; c < 32; ++c) { accA[c] = bfv[p * 32 + c]; accB[c] = accA[c]; }
  #pragma unroll 8
  for (int d = 0; d < 64; ++d) {
    unsigned xu = xs32[d * 64 + nl];
    float xa = __uint_as_float(xu << 16);
    float xbv = __uint_as_float(xu & 0xffff0000u);
    #pragma unroll
    for (int c4 = 0; c4 < 8; ++c4) {
      float4 w = *(const float4*)(W + d * 32 + c4 * 4);
      accA[c4*4+0] = fmaf(w.x, xa, accA[c4*4+0]); accB[c4*4+0] = fmaf(w.x, xbv, accB[c4*4+0]);
      accA[c4*4+1] = fmaf(w.y, xa, accA[c4*4+1]); accB[c4*4+1] = fmaf(w.y, xbv, accB[c4*4+1]);
      accA[c4*4+2] = fmaf(w.z, xa, accA[c4*4+2]); accB[c4*4+2] = fmaf(w.z, xbv, accB[c4*4+2]);
      accA[c4*4+3] = fmaf(w.w, xa, accA[c4*4+3]); accB[c4*4+3] = fmaf(w.w, xbv, accB[c4*4+3]);
    }
  }

  int blk = p / 3, m = p - blk * 3;
  int n = n0 + 2 * nl;
  if (m < 2) {
    ushort* dst = (m == 0) ? Qb : Kb;
    #pragma unroll
    for (int h = 0; h < 4; ++h) {
      size_t inst = ((size_t)blk * 96 + bt) * 4 + h;
      uint4 uA, uB;
      uA.x = pk2(accA[h*8+0], accA[h*8+1]); uA.y = pk2(accA[h*8+2], accA[h*8+3]);
      uA.z = pk2(accA[h*8+4], accA[h*8+5]); uA.w = pk2(accA[h*8+6], accA[h*8+7]);
      uB.x = pk2(accB[h*8+0], accB[h*8+1]); uB.y = pk2(accB[h*8+2], accB[h*8+3]);
      uB.z = pk2(accB[h*8+4], accB[h*8+5]); uB.w = pk2(accB[h*8+6], accB[h*8+7]);
      *(uint4*)(dst + (inst * 512 + n) * 8)     = uA;
      *(uint4*)(dst + (inst * 512 + n + 1) * 8) = uB;
    }
  } else {
    #pragma unroll
    for (int h = 0; h < 4; ++h) {
      size_t inst = ((size_t)blk * 96 + bt) * 4 + h;
      #pragma unroll
      for (int dd = 0; dd < 8; ++dd)
        *(unsigned*)(Vt + (inst * 8 + dd) * 512 + n) = pk2(accA[h*8+dd], accB[h*8+dd]);
    }
  }
}

// ---- MFMA attention: grid (h=4, bt=96, blk=2), 512 threads = 8 waves, 64 q-rows/wave ----
__global__ void __launch_bounds__(512) k_attn(const ushort* __restrict__ Qb,
    const ushort* __restrict__ Kb, const ushort* __restrict__ Vt,
    const unsigned* __restrict__ mbw, float* __restrict__ obuf) {
  __shared__ __align__(16) ushort Kl[512 * 12];   // K rows padded 8->12 (bank spread)
  __shared__ __align__(16) ushort Vl[9 * 520];    // V^T rows 0-7 + ones row 8, stride 520
  int h = blockIdx.x, bt = blockIdx.y, blk = blockIdx.z;
  int tid = threadIdx.x;
  size_t inst = ((size_t)blk * 96 + bt) * 4 + h;

  { // stage K: row tid (8 bf16 = 16B) -> Kl[tid*12 ..]
    uint4 kr = ((const uint4*)(Kb + inst * 4096))[tid];
    *(uint2*)&Kl[tid * 12]     = make_uint2(kr.x, kr.y);
    *(uint2*)&Kl[tid * 12 + 4] = make_uint2(kr.z, kr.w);
  }
  { // stage V^T + ones row
    const ushort* vp = Vt + inst * 4096;
    #pragma unroll
    for (int d = 0; d < 8; ++d) Vl[d * 520 + tid] = vp[d * 512 + tid];
    Vl[8 * 520 + tid] = 0x3F80;   // bf16 1.0
  }
  __syncthreads();

  int lane = tid & 63, lo = lane & 31, hi = lane >> 5, w = tid >> 6;
  int qbase = w * 64;

  // Q fragments (B-operand of QK): lane holds Q[q][4*hi + i]
  bf16x4 qf[2];
  #pragma unroll
  for (int s = 0; s < 2; ++s) {
    int q = qbase + s * 32 + lo;
    qf[s] = bcast<bf16x4>(*(const uint2*)(Qb + inst * 4096 + q * 8 + hi * 4));
  }

  f32x16 acc[2], zc;
  #pragma unroll
  for (int i = 0; i < 16; ++i) { acc[0][i] = 0.f; acc[1][i] = 0.f; zc[i] = 0.f; }

  for (int t16 = 0; t16 < 16; ++t16) {
    // K fragment (A-operand): lane holds K[t16*32+lo][4*hi + i]
    bf16x4 kf = bcast<bf16x4>(*(const uint2*)&Kl[(t16 * 32 + lo) * 12 + 4 * hi]);
    // V^T fragments (A-operand of AV): lane holds V^T[lo][kv = t16*32 + 8c + 4hi + i]
    bf16x4 vf[4];
    int vrow = (lo < 8 ? lo : 8) * 520 + t16 * 32 + 4 * hi;
    #pragma unroll
    for (int c = 0; c < 4; ++c) {
      uint2 vv = *(const uint2*)&Vl[vrow + 8 * c];
      if (lo > 8) { vv.x = 0u; vv.y = 0u; }   // rows 9..31 of A are zero
      vf[c] = bcast<bf16x4>(vv);
    }
    #pragma unroll
    for (int s = 0; s < 2; ++s) {
      // S^T tile = K · Q^T : D[kv][q], lane = q-col, regs = kv-rows
      f32x16 st = __builtin_amdgcn_mfma_f32_32x32x8bf16_1k(kf, qf[s], zc, 0, 0, 0);
      unsigned mwh = 0u;
      if (blk == 1) {
        int q = qbase + s * 32 + lo;
        mwh = mbw[q * 16 + t16] >> (4 * hi);
      }
      unsigned u[8];
      #pragma unroll
      for (int j = 0; j < 8; ++j) {
        // rows r0=2j, r1=2j+1 -> mask cols c0, c0+1 (c(r) = (r&3) + 8*(r>>2))
        float p0 = fast_exp2(st[2*j]);
        float p1 = fast_exp2(st[2*j+1]);
        if (blk == 1) {
          int c0 = ((2*j) & 3) + 8 * ((2*j) >> 2);
          if ((mwh >> c0) & 1u) p0 = 0.f;
          if ((mwh >> (c0 + 1)) & 1u) p1 = 0.f;
        }
        // truncating bf16 pack: low half = p0, high half = p1
        u[j] = (__float_as_uint(p0) >> 16) | (__float_as_uint(p1) & 0xffff0000u);
      }
      // O^T += V^T · P^T in 4 chunks of 8 kv; D regs 4c..4c+3 are B elems 0..3 in-lane
      #pragma unroll
      for (int c = 0; c < 4; ++c) {
        uint2 pu = make_uint2(u[2 * c], u[2 * c + 1]);
        acc[s] = __builtin_amdgcn_mfma_f32_32x32x8bf16_1k(vf[c], bcast<bf16x4>(pu), acc[s], 0, 0, 0);
      }
    }
  }

  // epilogue: lane holds O^T[d = {0..3}+4hi][q], l = acc[4] on hi=0 lanes
  int b = bt / 12, t = bt - b * 12;
  #pragma unroll
  for (int s = 0; s < 2; ++s) {
    float l = __shfl(acc[s][4], lo);
    float inv = __builtin_amdgcn_rcpf(l);
    int q = qbase + s * 32 + lo;
    int g = (h * 12 + t) * 128 + (q >> 2);
    float* ob = obuf + (size_t)blk * 1572864 + ((size_t)b * 6144 + g) * 32 + (q & 3) * 8 + 4 * hi;
    *(float4*)ob = make_float4(acc[s][0] * inv, acc[s][1] * inv, acc[s][2] * inv, acc[s][3] * inv);
  }
}

// ---- epilogue with LDS transpose: out[b][c][t'][n'] = relu(obuf[..] + x[..]) ----
__global__ void __launch_bounds__(256) k_out(const float* __restrict__ x, const float* __restrict__ obuf,
                     float* __restrict__ out) {
  __shared__ float tile[64][65];
  int nc = blockIdx.x;   // 0..7
  int tq = blockIdx.y;   // 0..11
  int b  = blockIdx.z;   // 0..7
  int n0 = nc * 64;
  #pragma unroll
  for (int it = 0; it < 16; ++it) {
    int i = it * 256 + threadIdx.x;
    int nl = i >> 6, c = i & 63;
    int sel = c >> 5;
    tile[nl][c] = obuf[(size_t)sel * 1572864 +
                       ((size_t)b * 6144 + (size_t)(n0 + nl) * 12 + tq) * 32 + (c & 31)];
  }
  __syncthreads();
  #pragma unroll
  for (int it = 0; it < 16; ++it) {
    int i = it * 256 + threadIdx.x;
    int c = i >> 6, nl = i & 63;
    size_t oi = ((size_t)(b * 64 + c) * 12 + tq) * 512 + n0 + nl;
    out[oi] = fmaxf(tile[nl][c] + x[oi], 0.f);
  }
}

extern "C" void kernel_launch(void* const* d_in, const int* in_sizes, int n_in,
                              void* d_out, int out_size, void* d_ws, size_t ws_size,
                              hipStream_t stream) {
  const float* x        = (const float*)d_in[0];
  const int*   geo_mask = (const int*)d_in[1];
  const float* w_proj1  = (const float*)d_in[2];
  const float* b_proj1  = (const float*)d_in[3];
  ProjW pw;
  // blk 0 = plain (x_v), blk 1 = geo (x_geo_v); m: 0=q,1=k,2=v
  pw.w[0] = (const float*)d_in[10]; pw.b[0] = (const float*)d_in[11];  // wq, bq
  pw.w[1] = (const float*)d_in[12]; pw.b[1] = (const float*)d_in[13];  // wk, bk
  pw.w[2] = (const float*)d_in[14]; pw.b[2] = (const float*)d_in[15];  // wv, bv
  pw.w[3] = (const float*)d_in[4];  pw.b[3] = (const float*)d_in[5];   // wgq, bgq
  pw.w[4] = (const float*)d_in[6];  pw.b[4] = (const float*)d_in[7];   // wgk, bgk
  pw.w[5] = (const float*)d_in[8];  pw.b[5] = (const float*)d_in[9];   // wgv, bgv
  float* out = (float*)d_out;

  float* ws = (float*)d_ws;
  float* obuf = ws;                               // [2][8][512][12][32]   = 3,145,728 f32
  float* wfT  = ws + 3145728;                     // [6][64][32]           = 12,288 f32
  float* bfv  = ws + 3158016;                     // [6][32]               = 192 f32
  unsigned* mbw = (unsigned*)(ws + 3158208);      // [512][16] u32         = 8,192 u32
  ushort* Qb = (ushort*)(ws + 3166400);           // [2][96][4][512][8]    = 3,145,728 u16
  ushort* Kb = (ushort*)(ws + 4739264);           // same
  ushort* Vt = (ushort*)(ws + 6312128);           // [2][96][4][8][512]

  k_pack_mask<<<32, 256, 0, stream>>>(geo_mask, mbw);
  k_wfuse<<<6, 64, 0, stream>>>(pw, w_proj1, b_proj1, wfT, bfv);
  k_qkv<<<dim3(96, 4), 384, 0, stream>>>(x, wfT, bfv, Qb, Kb, Vt);
  k_attn<<<dim3(4, 96, 2), 512, 0, stream>>>(Qb, Kb, Vt, mbw, obuf);
  k_out<<<dim3(8, 12, 8), 256, 0, stream>>>(x, obuf, out);
}

// Round 10
// 162.755 us; speedup vs baseline: 2.7795x; 1.1667x over previous
//
#include <hip/hip_runtime.h>
#include <hip/hip_bf16.h>

typedef __attribute__((ext_vector_type(4))) short bf16x4;
typedef __attribute__((ext_vector_type(16))) float f32x16;

#define SCALE 0.35355339059327373f
#define LOG2E 1.4426950408889634f

struct ProjW { const float* w[6]; const float* b[6]; };

template<typename T, typename F>
__device__ inline T bcast(F f) { union { F a; T b; } u; u.a = f; return u.b; }

// truncating bf16 pack: lo16 = bf16(a), hi16 = bf16(b)   [proven in round-8 k_attn]
__device__ inline unsigned tpk2(float a, float b) {
  return (__float_as_uint(a) >> 16) | (__float_as_uint(b) & 0xffff0000u);
}

__device__ inline float fast_exp2(float x) {
  float r;
  asm("v_exp_f32 %0, %1" : "=v"(r) : "v"(x));
  return r;
}

// ---- pack geo_mask [512][512] int -> bitmask [512][16] u32 ----
__global__ void k_pack_mask(const int* __restrict__ mask, unsigned* __restrict__ mbw) {
  int w = blockIdx.x * 256 + threadIdx.x;   // 0..8191
  int n = w >> 4, wi = w & 15;
  const int* mp = mask + n * 512 + wi * 32;
  unsigned bits = 0u;
  #pragma unroll
  for (int j = 0; j < 32; ++j) bits |= (mp[j] != 0) ? (1u << j) : 0u;
  mbw[w] = bits;
}

// ---- fused weights: wfb[p*32+c][68] bf16 = (W_p*W1) row c ; bfv[p][32] f32 ----
__global__ void k_wfuse(ProjW pw, const float* __restrict__ w1, const float* __restrict__ b1,
                        ushort* __restrict__ wfb, float* __restrict__ bfv) {
  int p = blockIdx.x;       // 0..5
  int d = threadIdx.x;      // 0..63
  const float* W = pw.w[p];
  float sc = (p % 3 == 0) ? SCALE * LOG2E : 1.0f;   // fold softmax scale + log2e into q
  float col[32];
  #pragma unroll
  for (int e = 0; e < 32; ++e) col[e] = w1[e * 64 + d];
  for (int c = 0; c < 32; ++c) {
    float a = 0.f;
    #pragma unroll
    for (int e = 0; e < 32; ++e) a = fmaf(W[c * 32 + e], col[e], a);
    __hip_bfloat16 hb = __float2bfloat16(a * sc);
    wfb[(p * 32 + c) * 68 + d] = *(ushort*)&hb;
  }
  if (d < 32) {
    float a = pw.b[p][d];
    #pragma unroll
    for (int e = 0; e < 32; ++e) a = fmaf(W[d * 32 + e], b1[e], a);
    bfv[p * 32 + d] = a * sc;
  }
}

// ---- MFMA projections: grid (bt=96, ch=8), 384 thr = 6 waves (wave = proj ci) ----
// out^T[32c x 32n] tiles = Wf(A, rows=c) x x(B, cols=n), K=64 in 8 steps of 8.
__global__ void __launch_bounds__(384) k_qkv(const float* __restrict__ x,
    const ushort* __restrict__ wfb, const float* __restrict__ bfv,
    ushort* __restrict__ Qb, ushort* __restrict__ Kb, ushort* __restrict__ Vt) {
  __shared__ __align__(16) ushort Wl[192 * 68];   // 25.5 KB
  int bt = blockIdx.x, ch = blockIdx.y;
  int tid = threadIdx.x;
  int b = bt / 12, t = bt - b * 12;
  for (int i = tid; i < 6528; i += 384)
    ((unsigned*)Wl)[i] = ((const unsigned*)wfb)[i];
  __syncthreads();

  int lane = tid & 63, ci = tid >> 6;     // ci = p, wave-uniform
  int lo = lane & 31, hi = lane >> 5;
  int blk = ci / 3, m = ci - blk * 3;

  // A-frags: Wf row 32ci+lo, d = 8ks + 4hi + {0..3}  (cached for both tiles)
  bf16x4 af[8];
  #pragma unroll
  for (int ks = 0; ks < 8; ++ks)
    af[ks] = *(const bf16x4*)&Wl[(32 * ci + lo) * 68 + 8 * ks + 4 * hi];

  // bias per acc reg: c_local = (r&3) + 8*(r>>2) + 4*hi
  float bias[16];
  #pragma unroll
  for (int r = 0; r < 16; ++r)
    bias[r] = bfv[ci * 32 + (r & 3) + 8 * (r >> 2) + 4 * hi];

  const float* xb = x + ((size_t)b * 768 + t) * 512;   // + d*6144 + n
  for (int tile = 0; tile < 2; ++tile) {
    int n = ch * 64 + tile * 32 + lo;
    // B-frags: x[d][n], d = 8ks + 4hi + i  (32 strided dwords, coalesced along n)
    uint2 bfr[8];
    #pragma unroll
    for (int ks = 0; ks < 8; ++ks) {
      int d0 = 8 * ks + 4 * hi;
      float x0 = xb[(size_t)(d0 + 0) * 6144 + n];
      float x1 = xb[(size_t)(d0 + 1) * 6144 + n];
      float x2 = xb[(size_t)(d0 + 2) * 6144 + n];
      float x3 = xb[(size_t)(d0 + 3) * 6144 + n];
      bfr[ks] = make_uint2(tpk2(x0, x1), tpk2(x2, x3));
    }
    f32x16 acc;
    #pragma unroll
    for (int i = 0; i < 16; ++i) acc[i] = 0.f;
    #pragma unroll
    for (int ks = 0; ks < 8; ++ks)
      acc = __builtin_amdgcn_mfma_f32_32x32x8bf16_1k(af[ks], bcast<bf16x4>(bfr[ks]), acc, 0, 0, 0);
    #pragma unroll
    for (int r = 0; r < 16; ++r) acc[r] += bias[r];

    if (m < 2) {
      ushort* dst = (m == 0) ? Qb : Kb;
      #pragma unroll
      for (int h = 0; h < 4; ++h) {
        size_t inst = ((size_t)blk * 96 + bt) * 4 + h;
        // head h channels 8h+4hi+{0..3} live in regs 4h..4h+3 of this half
        unsigned u0 = tpk2(acc[4*h + 0], acc[4*h + 1]);
        unsigned u1 = tpk2(acc[4*h + 2], acc[4*h + 3]);
        unsigned u0x = __shfl_xor(u0, 32);
        unsigned u1x = __shfl_xor(u1, 32);
        if (hi == 0) {
          uint4 u = make_uint4(u0, u1, u0x, u1x);
          *(uint4*)(dst + (inst * 512 + n) * 8) = u;
        }
      }
    } else {
      #pragma unroll
      for (int j = 0; j < 8; ++j) {
        int r = 2 * j;
        int h = r >> 2;
        int dd = (r & 3) + 4 * hi;
        size_t inst = ((size_t)blk * 96 + bt) * 4 + h;
        unsigned u = tpk2(acc[r], acc[r + 1]);
        Vt[(inst * 8 + dd) * 512 + n]     = (ushort)(u & 0xffffu);
        Vt[(inst * 8 + dd + 1) * 512 + n] = (ushort)(u >> 16);
      }
    }
  }
}

// ---- MFMA attention: grid (h=4, bt=96, blk=2), 512 threads = 8 waves, 64 q-rows/wave ----
__global__ void __launch_bounds__(512) k_attn(const ushort* __restrict__ Qb,
    const ushort* __restrict__ Kb, const ushort* __restrict__ Vt,
    const unsigned* __restrict__ mbw, float* __restrict__ obuf) {
  __shared__ __align__(16) ushort Kl[512 * 12];   // K rows padded 8->12 (bank spread)
  __shared__ __align__(16) ushort Vl[9 * 520];    // V^T rows 0-7 + ones row 8, stride 520
  int h = blockIdx.x, bt = blockIdx.y, blk = blockIdx.z;
  int tid = threadIdx.x;
  size_t inst = ((size_t)blk * 96 + bt) * 4 + h;

  { // stage K: row tid (8 bf16 = 16B) -> Kl[tid*12 ..]
    uint4 kr = ((const uint4*)(Kb + inst * 4096))[tid];
    *(uint2*)&Kl[tid * 12]     = make_uint2(kr.x, kr.y);
    *(uint2*)&Kl[tid * 12 + 4] = make_uint2(kr.z, kr.w);
  }
  { // stage V^T + ones row
    const ushort* vp = Vt + inst * 4096;
    #pragma unroll
    for (int d = 0; d < 8; ++d) Vl[d * 520 + tid] = vp[d * 512 + tid];
    Vl[8 * 520 + tid] = 0x3F80;   // bf16 1.0
  }
  __syncthreads();

  int lane = tid & 63, lo = lane & 31, hi = lane >> 5, w = tid >> 6;
  int qbase = w * 64;

  // Q fragments (B-operand of QK): lane holds Q[q][4*hi + i]
  bf16x4 qf[2];
  #pragma unroll
  for (int s = 0; s < 2; ++s) {
    int q = qbase + s * 32 + lo;
    qf[s] = bcast<bf16x4>(*(const uint2*)(Qb + inst * 4096 + q * 8 + hi * 4));
  }

  f32x16 acc[2], zc;
  #pragma unroll
  for (int i = 0; i < 16; ++i) { acc[0][i] = 0.f; acc[1][i] = 0.f; zc[i] = 0.f; }

  for (int t16 = 0; t16 < 16; ++t16) {
    // K fragment (A-operand): lane holds K[t16*32+lo][4*hi + i]
    bf16x4 kf = bcast<bf16x4>(*(const uint2*)&Kl[(t16 * 32 + lo) * 12 + 4 * hi]);
    // V^T fragments (A-operand of AV): lane holds V^T[lo][kv = t16*32 + 8c + 4hi + i]
    bf16x4 vf[4];
    int vrow = (lo < 8 ? lo : 8) * 520 + t16 * 32 + 4 * hi;
    #pragma unroll
    for (int c = 0; c < 4; ++c) {
      uint2 vv = *(const uint2*)&Vl[vrow + 8 * c];
      if (lo > 8) { vv.x = 0u; vv.y = 0u; }   // rows 9..31 of A are zero
      vf[c] = bcast<bf16x4>(vv);
    }
    #pragma unroll
    for (int s = 0; s < 2; ++s) {
      // S^T tile = K · Q^T : D[kv][q], lane = q-col, regs = kv-rows
      f32x16 st = __builtin_amdgcn_mfma_f32_32x32x8bf16_1k(kf, qf[s], zc, 0, 0, 0);
      unsigned mwh = 0u;
      if (blk == 1) {
        int q = qbase + s * 32 + lo;
        mwh = mbw[q * 16 + t16] >> (4 * hi);
      }
      unsigned u[8];
      #pragma unroll
      for (int j = 0; j < 8; ++j) {
        // rows r0=2j, r1=2j+1 -> mask cols c0, c0+1 (c(r) = (r&3) + 8*(r>>2))
        float p0 = fast_exp2(st[2*j]);
        float p1 = fast_exp2(st[2*j+1]);
        if (blk == 1) {
          int c0 = ((2*j) & 3) + 8 * ((2*j) >> 2);
          if ((mwh >> c0) & 1u) p0 = 0.f;
          if ((mwh >> (c0 + 1)) & 1u) p1 = 0.f;
        }
        u[j] = tpk2(p0, p1);
      }
      // O^T += V^T · P^T in 4 chunks of 8 kv; D regs 4c..4c+3 are B elems 0..3 in-lane
      #pragma unroll
      for (int c = 0; c < 4; ++c) {
        uint2 pu = make_uint2(u[2 * c], u[2 * c + 1]);
        acc[s] = __builtin_amdgcn_mfma_f32_32x32x8bf16_1k(vf[c], bcast<bf16x4>(pu), acc[s], 0, 0, 0);
      }
    }
  }

  // epilogue: lane holds O^T[d = {0..3}+4hi][q], l = acc[4] on hi=0 lanes
  int b = bt / 12, t = bt - b * 12;
  #pragma unroll
  for (int s = 0; s < 2; ++s) {
    float l = __shfl(acc[s][4], lo);
    float inv = __builtin_amdgcn_rcpf(l);
    int q = qbase + s * 32 + lo;
    int g = (h * 12 + t) * 128 + (q >> 2);
    float* ob = obuf + (size_t)blk * 1572864 + ((size_t)b * 6144 + g) * 32 + (q & 3) * 8 + 4 * hi;
    *(float4*)ob = make_float4(acc[s][0] * inv, acc[s][1] * inv, acc[s][2] * inv, acc[s][3] * inv);
  }
}

// ---- epilogue with LDS transpose: out[b][c][t'][n'] = relu(obuf[..] + x[..]) ----
__global__ void __launch_bounds__(256) k_out(const float* __restrict__ x, const float* __restrict__ obuf,
                     float* __restrict__ out) {
  __shared__ float tile[64][65];
  int nc = blockIdx.x;   // 0..7
  int tq = blockIdx.y;   // 0..11
  int b  = blockIdx.z;   // 0..7
  int n0 = nc * 64;
  #pragma unroll
  for (int it = 0; it < 16; ++it) {
    int i = it * 256 + threadIdx.x;
    int nl = i >> 6, c = i & 63;
    int sel = c >> 5;
    tile[nl][c] = obuf[(size_t)sel * 1572864 +
                       ((size_t)b * 6144 + (size_t)(n0 + nl) * 12 + tq) * 32 + (c & 31)];
  }
  __syncthreads();
  #pragma unroll
  for (int it = 0; it < 16; ++it) {
    int i = it * 256 + threadIdx.x;
    int c = i >> 6, nl = i & 63;
    size_t oi = ((size_t)(b * 64 + c) * 12 + tq) * 512 + n0 + nl;
    out[oi] = fmaxf(tile[nl][c] + x[oi], 0.f);
  }
}

extern "C" void kernel_launch(void* const* d_in, const int* in_sizes, int n_in,
                              void* d_out, int out_size, void* d_ws, size_t ws_size,
                              hipStream_t stream) {
  const float* x        = (const float*)d_in[0];
  const int*   geo_mask = (const int*)d_in[1];
  const float* w_proj1  = (const float*)d_in[2];
  const float* b_proj1  = (const float*)d_in[3];
  ProjW pw;
  // blk 0 = plain (x_v), blk 1 = geo (x_geo_v); m: 0=q,1=k,2=v
  pw.w[0] = (const float*)d_in[10]; pw.b[0] = (const float*)d_in[11];  // wq, bq
  pw.w[1] = (const float*)d_in[12]; pw.b[1] = (const float*)d_in[13];  // wk, bk
  pw.w[2] = (const float*)d_in[14]; pw.b[2] = (const float*)d_in[15];  // wv, bv
  pw.w[3] = (const float*)d_in[4];  pw.b[3] = (const float*)d_in[5];   // wgq, bgq
  pw.w[4] = (const float*)d_in[6];  pw.b[4] = (const float*)d_in[7];   // wgk, bgk
  pw.w[5] = (const float*)d_in[8];  pw.b[5] = (const float*)d_in[9];   // wgv, bgv
  float* out = (float*)d_out;

  float* ws = (float*)d_ws;
  float* obuf = ws;                               // [2][8][512][12][32]   = 3,145,728 f32
  float* bfv  = ws + 3145728;                     // [6][32] f32           = 192
  ushort* wfb = (ushort*)(ws + 3145920);          // [192][68] bf16        = 13,056 u16 (6528 f32)
  unsigned* mbw = (unsigned*)(ws + 3152448);      // [512][16] u32         = 8,192
  ushort* Qb = (ushort*)(ws + 3160640);           // [2][96][4][512][8]    = 3,145,728 u16
  ushort* Kb = (ushort*)(ws + 4733504);           // same
  ushort* Vt = (ushort*)(ws + 6306368);           // [2][96][4][8][512]

  k_pack_mask<<<32, 256, 0, stream>>>(geo_mask, mbw);
  k_wfuse<<<6, 64, 0, stream>>>(pw, w_proj1, b_proj1, wfb, bfv);
  k_qkv<<<dim3(96, 8), 384, 0, stream>>>(x, wfb, bfv, Qb, Kb, Vt);
  k_attn<<<dim3(4, 96, 2), 512, 0, stream>>>(Qb, Kb, Vt, mbw, obuf);
  k_out<<<dim3(8, 12, 8), 256, 0, stream>>>(x, obuf, out);
}